// Round 8
// baseline (364.431 us; speedup 1.0000x reference)
//
#include <hip/hip_runtime.h>
#include <hip/hip_bf16.h>

typedef unsigned short u16;
typedef short bf16x4 __attribute__((ext_vector_type(4)));
typedef short bf16x8 __attribute__((ext_vector_type(8)));
typedef float f32x4 __attribute__((ext_vector_type(4)));

#define NEG_BIG (-1e30f)
#define SCL 0.18033688f   // 0.125 * log2(e): Q pre-scaled so scores are in log2 units

__device__ __forceinline__ u16 f2bf(float f) {
    union { float f; unsigned int u; } x; x.f = f;
    unsigned int r = x.u + 0x7fffu + ((x.u >> 16) & 1u);
    return (u16)(r >> 16);
}

// hardware RNE pack of two f32 -> 2x bf16 in one u32 (T12 primitive)
__device__ __forceinline__ unsigned cvtpk(float lo, float hi) {
    unsigned r;
    asm("v_cvt_pk_bf16_f32 %0, %1, %2" : "=v"(r) : "v"(lo), "v"(hi));
    return r;
}

__device__ __forceinline__ f32x4 mfma16(bf16x4 a, bf16x4 b, f32x4 c) {
#if __has_builtin(__builtin_amdgcn_mfma_f32_16x16x16bf16_1k)
    return __builtin_amdgcn_mfma_f32_16x16x16bf16_1k(a, b, c, 0, 0, 0);
#else
    asm("v_mfma_f32_16x16x16_bf16 %0, %1, %2, %0" : "+v"(c) : "v"(a), "v"(b));
    return c;
#endif
}

__device__ __forceinline__ void dma16(const u16* g, const u16* lds) {
    __builtin_amdgcn_global_load_lds(
        (const __attribute__((address_space(1))) unsigned int*)g,
        (__attribute__((address_space(3))) unsigned int*)lds, 16, 0, 0);
}

__device__ __forceinline__ bf16x8 sfrag(const u16* lds, int row, int kb8) {
    int slot = row * 8 + (kb8 ^ (row & 7));
    return *(const bf16x8*)(lds + slot * 8);
}

// b64 V^T fragment for 16x16x16 PV
__device__ __forceinline__ bf16x4 vfrag(const u16* lds, int row, int kb, int lhi) {
    int c = kb * 2 + (lhi >> 1);
    int slot = row * 8 + (c ^ (row & 7));
    return *(const bf16x4*)(lds + slot * 8 + (lhi & 1) * 4);
}

// ---------------- fused fp32 -> bf16 convert ----------------
__global__ __launch_bounds__(256) void cvt_all(const float* __restrict__ x,
                                               const float* __restrict__ wq,
                                               const float* __restrict__ wk,
                                               const float* __restrict__ wv,
                                               const float* __restrict__ wo,
                                               u16* __restrict__ xb, u16* __restrict__ wqb,
                                               u16* __restrict__ wkb, u16* __restrict__ wvb,
                                               u16* __restrict__ wob) {
    size_t i = (size_t)blockIdx.x * 256 + threadIdx.x;
    const float* s; u16* d; size_t off;
    if      (i < 1048576) { s = x;  d = xb;  off = i; }
    else if (i < 1572864) { s = wq; d = wqb; off = i - 1048576; }
    else if (i < 1703936) { s = wk; d = wkb; off = i - 1572864; }
    else if (i < 1835008) { s = wv; d = wvb; off = i - 1703936; }
    else                  { s = wo; d = wob; off = i - 1835008; }
    const float* p = s + off * 8;
    float4 a = *(const float4*)p;
    float4 b = *(const float4*)(p + 4);
    union { unsigned u[4]; bf16x8 v; } r;
    r.u[0] = cvtpk(a.x, a.y);
    r.u[1] = cvtpk(a.z, a.w);
    r.u[2] = cvtpk(b.x, b.y);
    r.u[3] = cvtpk(b.z, b.w);
    *(bf16x8*)(d + off * 8) = r.v;
}

// ---------------- bf16 GEMM (m97-style), fp32 output ----------------
__global__ __launch_bounds__(256) void gemm_bt(const u16* __restrict__ A,
                                               const u16* __restrict__ Bt,
                                               float* __restrict__ C,
                                               int M, int N, int K) {
    __shared__ u16 As[8192];
    __shared__ u16 Bs[8192];
    const int t = threadIdx.x;
    const int wave = t >> 6, lane = t & 63;
    const int wm = (wave >> 1) * 64, wn = (wave & 1) * 64;
    const int lhi = lane >> 4, llo = lane & 15;
    const int m0 = blockIdx.y * 128, n0 = blockIdx.x * 128;
    const int wbase = wave * 64;

    f32x4 acc[4][4] = {};
    for (int k0 = 0; k0 < K; k0 += 64) {
        const u16* Ab = A + (size_t)m0 * K + k0;
        const u16* Bb = Bt + (size_t)n0 * K + k0;
#pragma unroll
        for (int i = 0; i < 4; ++i) {
            int s = i * 256 + t;
            int row = s >> 3, gch = (s & 7) ^ (row & 7);
            dma16(Ab + (size_t)row * K + gch * 8, As + (i * 256 + wbase) * 8);
            dma16(Bb + (size_t)row * K + gch * 8, Bs + (i * 256 + wbase) * 8);
        }
        __syncthreads();
#pragma unroll
        for (int ks = 0; ks < 2; ++ks) {
            const int kb = ks * 4 + lhi;
            bf16x8 af[4], bfg[4];
#pragma unroll
            for (int mi = 0; mi < 4; ++mi) af[mi] = sfrag(As, wm + mi * 16 + llo, kb);
#pragma unroll
            for (int ni = 0; ni < 4; ++ni) bfg[ni] = sfrag(Bs, wn + ni * 16 + llo, kb);
#pragma unroll
            for (int mi = 0; mi < 4; ++mi)
#pragma unroll
                for (int ni = 0; ni < 4; ++ni)
                    acc[mi][ni] = __builtin_amdgcn_mfma_f32_16x16x32_bf16(
                        af[mi], bfg[ni], acc[mi][ni], 0, 0, 0);
        }
        __syncthreads();
    }
#pragma unroll
    for (int mi = 0; mi < 4; ++mi)
#pragma unroll
        for (int ni = 0; ni < 4; ++ni)
#pragma unroll
            for (int r = 0; r < 4; ++r) {
                int row = m0 + wm + mi * 16 + lhi * 4 + r;
                int col = n0 + wn + ni * 16 + llo;
                C[(size_t)row * N + col] = acc[mi][ni][r];
            }
}

// ---------------- merged Q/K/V projection ----------------
// bx 0..15: Q [4096][2048] bf16, PRE-SCALED by SCL | bx 16..19: K | bx 20..23: Vt
__global__ __launch_bounds__(256) void gemm_qkv(const u16* __restrict__ A,
                                                const u16* __restrict__ Wq,
                                                const u16* __restrict__ Wk,
                                                const u16* __restrict__ Wv,
                                                u16* __restrict__ Qout,
                                                u16* __restrict__ Kout,
                                                u16* __restrict__ Vtout) {
    const int K = 2048;
    __shared__ u16 As[8192];
    __shared__ u16 Bs[8192];
    const int t = threadIdx.x;
    const int wave = t >> 6, lane = t & 63;
    const int wm = (wave >> 1) * 64, wn = (wave & 1) * 64;
    const int lhi = lane >> 4, llo = lane & 15;
    const int m0 = blockIdx.y * 128;
    const int bx = blockIdx.x;
    const int kind = (bx < 16) ? 0 : (bx < 20 ? 1 : 2);
    const int n0 = (kind == 0) ? bx * 128 : (bx & 3) * 128;
    const u16* Bt = ((kind == 0) ? Wq : (kind == 1) ? Wk : Wv) + (size_t)n0 * K;
    const int wbase = wave * 64;

    f32x4 acc[4][4] = {};
    for (int k0 = 0; k0 < K; k0 += 64) {
        const u16* Ab = A + (size_t)m0 * K + k0;
        const u16* Bb = Bt + k0;
#pragma unroll
        for (int i = 0; i < 4; ++i) {
            int s = i * 256 + t;
            int row = s >> 3, gch = (s & 7) ^ (row & 7);
            dma16(Ab + (size_t)row * K + gch * 8, As + (i * 256 + wbase) * 8);
            dma16(Bb + (size_t)row * K + gch * 8, Bs + (i * 256 + wbase) * 8);
        }
        __syncthreads();
#pragma unroll
        for (int ks = 0; ks < 2; ++ks) {
            const int kb = ks * 4 + lhi;
            bf16x8 af[4], bfg[4];
#pragma unroll
            for (int mi = 0; mi < 4; ++mi) af[mi] = sfrag(As, wm + mi * 16 + llo, kb);
#pragma unroll
            for (int ni = 0; ni < 4; ++ni) bfg[ni] = sfrag(Bs, wn + ni * 16 + llo, kb);
#pragma unroll
            for (int mi = 0; mi < 4; ++mi)
#pragma unroll
                for (int ni = 0; ni < 4; ++ni)
                    acc[mi][ni] = __builtin_amdgcn_mfma_f32_16x16x32_bf16(
                        af[mi], bfg[ni], acc[mi][ni], 0, 0, 0);
        }
        __syncthreads();
    }

    if (kind == 0) {
#pragma unroll
        for (int mi = 0; mi < 4; ++mi)
#pragma unroll
            for (int ni = 0; ni < 4; ++ni)
#pragma unroll
                for (int r = 0; r < 4; ++r) {
                    int row = m0 + wm + mi * 16 + lhi * 4 + r;
                    int col = n0 + wn + ni * 16 + llo;
                    Qout[(size_t)row * 2048 + col] = f2bf(acc[mi][ni][r] * SCL);
                }
    } else if (kind == 1) {
#pragma unroll
        for (int mi = 0; mi < 4; ++mi)
#pragma unroll
            for (int ni = 0; ni < 4; ++ni)
#pragma unroll
                for (int r = 0; r < 4; ++r) {
                    int row = m0 + wm + mi * 16 + lhi * 4 + r;
                    int col = n0 + wn + ni * 16 + llo;
                    Kout[(size_t)row * 512 + col] = f2bf(acc[mi][ni][r]);
                }
    } else {
        // Vt[b][g][hd][s]: off = (col + (row>>11)*512)*2048 + (row&2047)
#pragma unroll
        for (int mi = 0; mi < 4; ++mi)
#pragma unroll
            for (int ni = 0; ni < 4; ++ni) {
                int row = m0 + wm + mi * 16 + lhi * 4;
                int col = n0 + wn + ni * 16 + llo;
                size_t off = ((size_t)col + (size_t)(row >> 11) * 512) * 2048 + (row & 2047);
                union { unsigned u[2]; short4 s; } v;
                v.u[0] = cvtpk(acc[mi][ni][0], acc[mi][ni][1]);
                v.u[1] = cvtpk(acc[mi][ni][2], acc[mi][ni][3]);
                *(short4*)(Vtout + off) = v.s;
            }
    }
}

// ---------------- flash GQA attention v7: fused paired q-tiles ----------------
// One kt-loop per block serves BOTH q-tiles (qa=127-x, qb=x). Since qb<64<=qa,
// ktmax_b < ktmax_a always: B-work runs while kt<=ktmax_b. K/V staged ONCE per
// block (was twice for the shared range); V-fragments read once feed both PVs.
// Work stays 33 units/block; stage counts (17..32) are rebalanced across CUs by
// the bijective bid->(x,bg) remap: each CU's 4 co-resident blocks get
// x in {q,q+16,q+32,q+48} (stage-sum 89..104) and the SAME (b,g) -> K/V L2-hot.
__global__ __launch_bounds__(256, 4) void attn7(const u16* __restrict__ Q,
                                                const u16* __restrict__ Kbuf,
                                                const u16* __restrict__ Vtb,
                                                u16* __restrict__ Ctx) {
    __shared__ u16 Ks[2][4096];
    __shared__ u16 Vs[2][4096];
    const int bid = (int)blockIdx.x;
    const int x  = ((bid >> 6) << 2) | (bid & 3);   // 0..63
    const int bg = (bid >> 2) & 15;
    const int b = bg >> 3, g = bg & 7;
    const int t = threadIdx.x, w = t >> 6, lane = t & 63;
    const int lhi = lane >> 4, llo = lane & 15;
    const int h = g * 4 + w;
    const int wbase = w * 64;

    const u16* Kp = Kbuf + (size_t)(b * 2048) * 512 + g * 64;
    const u16* Vp = Vtb + (size_t)bg * 64 * 2048;

    const int r0 = t >> 3,          g0 = (t & 7) ^ (r0 & 7);
    const int r1 = (256 + t) >> 3,  g1 = ((256 + t) & 7) ^ (r1 & 7);

    bf16x4 ones;
    ones[0] = ones[1] = ones[2] = ones[3] = (short)0x3F80;

    auto STAGE = [&](int kt, int bufi) {
        const u16* Kt = Kp + (size_t)kt * 64 * 512;
        const u16* Vt2 = Vp + kt * 64;
        u16* Kd = Ks[bufi]; u16* Vd = Vs[bufi];
        dma16(Kt + (size_t)r0 * 512 + g0 * 8, Kd + wbase * 8);
        dma16(Vt2 + (size_t)r0 * 2048 + g0 * 8, Vd + wbase * 8);
        dma16(Kt + (size_t)r1 * 512 + g1 * 8, Kd + (256 + wbase) * 8);
        dma16(Vt2 + (size_t)r1 * 2048 + g1 * 8, Vd + (256 + wbase) * 8);
    };

    const int qa = 127 - x, qb = x;
    const int ktmax_a = (qa * 16 + 15) >> 6;
    const int ktmax_b = (qb * 16 + 15) >> 6;    // always < ktmax_a

    const u16* Qpa = Q + ((size_t)(b * 2048 + qa * 16)) * 2048 + h * 64;
    const u16* Qpb = Q + ((size_t)(b * 2048 + qb * 16)) * 2048 + h * 64;
    bf16x8 aqa[2], aqb[2];
#pragma unroll
    for (int ks = 0; ks < 2; ++ks) {
        aqa[ks] = *(const bf16x8*)(Qpa + (size_t)llo * 2048 + ks * 32 + lhi * 8);
        aqb[ks] = *(const bf16x8*)(Qpb + (size_t)llo * 2048 + ks * 32 + lhi * 8);
    }

    f32x4 oa[4] = {}, ob[4] = {};
    f32x4 laca = {}, lacb = {};
    float ma = NEG_BIG, mb = NEG_BIG;

    STAGE(0, 0);
    asm volatile("s_waitcnt vmcnt(0)" ::: "memory");
    __builtin_amdgcn_s_barrier();

    for (int kt = 0; kt <= ktmax_a; ++kt) {
        const int cur = kt & 1;
        if (kt < ktmax_a) STAGE(kt + 1, cur ^ 1);
        const u16* Ksb = Ks[cur];
        const u16* Vsb = Vs[cur];
        const bool doB = (kt <= ktmax_b);

        // ---------- work A: QK^T + softmax -> pfa ----------
        bf16x4 pfa[4], pfb[4];
        {
            f32x4 st[4] = {};
            __builtin_amdgcn_s_setprio(1);
#pragma unroll
            for (int ks = 0; ks < 2; ++ks) {
                const int kb8 = ks * 4 + lhi;
                bf16x8 kf[4];
#pragma unroll
                for (int kb = 0; kb < 4; ++kb) kf[kb] = sfrag(Ksb, kb * 16 + llo, kb8);
#pragma unroll
                for (int kb = 0; kb < 4; ++kb)
                    st[kb] = __builtin_amdgcn_mfma_f32_16x16x32_bf16(
                        kf[kb], aqa[ks], st[kb], 0, 0, 0);
            }
            __builtin_amdgcn_s_setprio(0);
            if (kt * 64 + 63 > qa * 16) {
                int qg = qa * 16 + llo;
#pragma unroll
                for (int kb = 0; kb < 4; ++kb)
#pragma unroll
                    for (int r = 0; r < 4; ++r) {
                        int kg = kt * 64 + kb * 16 + lhi * 4 + r;
                        if (kg > qg) st[kb][r] = NEG_BIG;
                    }
            }
            float t0 = fmaxf(fmaxf(st[0][0], st[0][1]), st[0][2]);
            float t1 = fmaxf(fmaxf(st[0][3], st[1][0]), st[1][1]);
            float t2 = fmaxf(fmaxf(st[1][2], st[1][3]), st[2][0]);
            float t3 = fmaxf(fmaxf(st[2][1], st[2][2]), st[2][3]);
            float t4 = fmaxf(fmaxf(st[3][0], st[3][1]), st[3][2]);
            float mx = fmaxf(fmaxf(fmaxf(t0, t1), t2),
                             fmaxf(fmaxf(t3, t4), st[3][3]));
            mx = fmaxf(mx, __shfl_xor(mx, 16, 64));
            mx = fmaxf(mx, __shfl_xor(mx, 32, 64));
            if (__any(mx > ma + 8.0f)) {
                float mn = fmaxf(ma, mx);
                float alpha = exp2f(ma - mn);
                ma = mn;
#pragma unroll
                for (int hb = 0; hb < 4; ++hb) oa[hb] *= alpha;
                laca *= alpha;
            }
#pragma unroll
            for (int kb = 0; kb < 4; ++kb) {
                float p0 = exp2f(st[kb][0] - ma);
                float p1 = exp2f(st[kb][1] - ma);
                float p2 = exp2f(st[kb][2] - ma);
                float p3 = exp2f(st[kb][3] - ma);
                union { unsigned u[2]; bf16x4 v; } pu;
                pu.u[0] = cvtpk(p0, p1);
                pu.u[1] = cvtpk(p2, p3);
                pfa[kb] = pu.v;
            }
        }

        // ---------- work B (shared k-range): QK^T + softmax -> pfb ----------
        if (doB) {
            f32x4 st[4] = {};
            __builtin_amdgcn_s_setprio(1);
#pragma unroll
            for (int ks = 0; ks < 2; ++ks) {
                const int kb8 = ks * 4 + lhi;
                bf16x8 kf[4];
#pragma unroll
                for (int kb = 0; kb < 4; ++kb) kf[kb] = sfrag(Ksb, kb * 16 + llo, kb8);
#pragma unroll
                for (int kb = 0; kb < 4; ++kb)
                    st[kb] = __builtin_amdgcn_mfma_f32_16x16x32_bf16(
                        kf[kb], aqb[ks], st[kb], 0, 0, 0);
            }
            __builtin_amdgcn_s_setprio(0);
            if (kt * 64 + 63 > qb * 16) {
                int qg = qb * 16 + llo;
#pragma unroll
                for (int kb = 0; kb < 4; ++kb)
#pragma unroll
                    for (int r = 0; r < 4; ++r) {
                        int kg = kt * 64 + kb * 16 + lhi * 4 + r;
                        if (kg > qg) st[kb][r] = NEG_BIG;
                    }
            }
            float t0 = fmaxf(fmaxf(st[0][0], st[0][1]), st[0][2]);
            float t1 = fmaxf(fmaxf(st[0][3], st[1][0]), st[1][1]);
            float t2 = fmaxf(fmaxf(st[1][2], st[1][3]), st[2][0]);
            float t3 = fmaxf(fmaxf(st[2][1], st[2][2]), st[2][3]);
            float t4 = fmaxf(fmaxf(st[3][0], st[3][1]), st[3][2]);
            float mx = fmaxf(fmaxf(fmaxf(t0, t1), t2),
                             fmaxf(fmaxf(t3, t4), st[3][3]));
            mx = fmaxf(mx, __shfl_xor(mx, 16, 64));
            mx = fmaxf(mx, __shfl_xor(mx, 32, 64));
            if (__any(mx > mb + 8.0f)) {
                float mn = fmaxf(mb, mx);
                float alpha = exp2f(mb - mn);
                mb = mn;
#pragma unroll
                for (int hb = 0; hb < 4; ++hb) ob[hb] *= alpha;
                lacb *= alpha;
            }
#pragma unroll
            for (int kb = 0; kb < 4; ++kb) {
                float p0 = exp2f(st[kb][0] - mb);
                float p1 = exp2f(st[kb][1] - mb);
                float p2 = exp2f(st[kb][2] - mb);
                float p3 = exp2f(st[kb][3] - mb);
                union { unsigned u[2]; bf16x4 v; } pu;
                pu.u[0] = cvtpk(p0, p1);
                pu.u[1] = cvtpk(p2, p3);
                pfb[kb] = pu.v;
            }
        }

        // ---------- PV: V-fragments read once, feed both outputs ----------
        __builtin_amdgcn_s_setprio(1);
        if (doB) {
#pragma unroll
            for (int kb = 0; kb < 4; ++kb) {
                laca = mfma16(ones, pfa[kb], laca);
                lacb = mfma16(ones, pfb[kb], lacb);
            }
#pragma unroll
            for (int kb = 0; kb < 4; ++kb)
#pragma unroll
                for (int hb = 0; hb < 4; ++hb) {
                    bf16x4 vf = vfrag(Vsb, hb * 16 + llo, kb, lhi);
                    oa[hb] = mfma16(vf, pfa[kb], oa[hb]);
                    ob[hb] = mfma16(vf, pfb[kb], ob[hb]);
                }
        } else {
#pragma unroll
            for (int kb = 0; kb < 4; ++kb) laca = mfma16(ones, pfa[kb], laca);
#pragma unroll
            for (int kb = 0; kb < 4; ++kb)
#pragma unroll
                for (int hb = 0; hb < 4; ++hb) {
                    bf16x4 vf = vfrag(Vsb, hb * 16 + llo, kb, lhi);
                    oa[hb] = mfma16(vf, pfa[kb], oa[hb]);
                }
        }
        __builtin_amdgcn_s_setprio(0);

        asm volatile("s_waitcnt vmcnt(0)" ::: "memory");
        __builtin_amdgcn_s_barrier();
    }

    // ---------- epilogues ----------
    {
        float inv = 1.0f / laca[0];
        u16* Cp = Ctx + (size_t)(b * 2048 + qa * 16) * 2048 + h * 64;
#pragma unroll
        for (int hb = 0; hb < 4; ++hb) {
            union { unsigned u[2]; short4 s; } cu;
            cu.u[0] = cvtpk(oa[hb][0] * inv, oa[hb][1] * inv);
            cu.u[1] = cvtpk(oa[hb][2] * inv, oa[hb][3] * inv);
            *(short4*)(Cp + (size_t)llo * 2048 + hb * 16 + lhi * 4) = cu.s;
        }
    }
    {
        float inv = 1.0f / lacb[0];
        u16* Cp = Ctx + (size_t)(b * 2048 + qb * 16) * 2048 + h * 64;
#pragma unroll
        for (int hb = 0; hb < 4; ++hb) {
            union { unsigned u[2]; short4 s; } cu;
            cu.u[0] = cvtpk(ob[hb][0] * inv, ob[hb][1] * inv);
            cu.u[1] = cvtpk(ob[hb][2] * inv, ob[hb][3] * inv);
            *(short4*)(Cp + (size_t)llo * 2048 + hb * 16 + lhi * 4) = cu.s;
        }
    }
}

extern "C" void kernel_launch(void* const* d_in, const int* in_sizes, int n_in,
                              void* d_out, int out_size, void* d_ws, size_t ws_size,
                              hipStream_t stream) {
    const float* x  = (const float*)d_in[0];
    const float* Wq = (const float*)d_in[1];
    const float* Wk = (const float*)d_in[2];
    const float* Wv = (const float*)d_in[3];
    const float* Wo = (const float*)d_in[4];

    u16* xb  = (u16*)d_ws;
    u16* wqb = xb + 8388608;
    u16* wkb = wqb + 4194304;
    u16* wvb = wkb + 1048576;
    u16* wob = wvb + 1048576;
    u16* Kb  = wob + 4194304;
    u16* Vtb = Kb + 2097152;
    u16* Ctx = xb;               // overlay (xb dead after projections)
    u16* Qb  = (u16*)d_out;      // bf16 Q staged in fp32 out buffer
    float* out = (float*)d_out;

    cvt_all<<<dim3(9216), 256, 0, stream>>>(x, Wq, Wk, Wv, Wo, xb, wqb, wkb, wvb, wob);
    gemm_qkv<<<dim3(24, 32), 256, 0, stream>>>(xb, wqb, wkb, wvb, Qb, Kb, Vtb);
    attn7<<<dim3(1024), 256, 0, stream>>>(Qb, Kb, Vtb, Ctx);
    gemm_bt<<<dim3(16, 32), 256, 0, stream>>>(Ctx, wob, out, 4096, 2048, 2048);
}

// Round 9
// 320.580 us; speedup vs baseline: 1.1368x; 1.1368x over previous
//
#include <hip/hip_runtime.h>
#include <hip/hip_bf16.h>

typedef unsigned short u16;
typedef short bf16x4 __attribute__((ext_vector_type(4)));
typedef short bf16x8 __attribute__((ext_vector_type(8)));
typedef float f32x4 __attribute__((ext_vector_type(4)));

#define NEG_BIG (-1e30f)
#define SCL 0.18033688f   // 0.125 * log2(e): Q pre-scaled so scores are in log2 units

__device__ __forceinline__ u16 f2bf(float f) {
    union { float f; unsigned int u; } x; x.f = f;
    unsigned int r = x.u + 0x7fffu + ((x.u >> 16) & 1u);
    return (u16)(r >> 16);
}

// hardware RNE pack of two f32 -> 2x bf16 in one u32 (T12 primitive)
__device__ __forceinline__ unsigned cvtpk(float lo, float hi) {
    unsigned r;
    asm("v_cvt_pk_bf16_f32 %0, %1, %2" : "=v"(r) : "v"(lo), "v"(hi));
    return r;
}

__device__ __forceinline__ f32x4 mfma16(bf16x4 a, bf16x4 b, f32x4 c) {
#if __has_builtin(__builtin_amdgcn_mfma_f32_16x16x16bf16_1k)
    return __builtin_amdgcn_mfma_f32_16x16x16bf16_1k(a, b, c, 0, 0, 0);
#else
    asm("v_mfma_f32_16x16x16_bf16 %0, %1, %2, %0" : "+v"(c) : "v"(a), "v"(b));
    return c;
#endif
}

__device__ __forceinline__ void dma16(const u16* g, const u16* lds) {
    __builtin_amdgcn_global_load_lds(
        (const __attribute__((address_space(1))) unsigned int*)g,
        (__attribute__((address_space(3))) unsigned int*)lds, 16, 0, 0);
}

__device__ __forceinline__ bf16x8 sfrag(const u16* lds, int row, int kb8) {
    int slot = row * 8 + (kb8 ^ (row & 7));
    return *(const bf16x8*)(lds + slot * 8);
}

// b64 V^T fragment for 16x16x16 PV
__device__ __forceinline__ bf16x4 vfrag(const u16* lds, int row, int kb, int lhi) {
    int c = kb * 2 + (lhi >> 1);
    int slot = row * 8 + (c ^ (row & 7));
    return *(const bf16x4*)(lds + slot * 8 + (lhi & 1) * 4);
}

// ---------------- fused fp32 -> bf16 convert ----------------
__global__ __launch_bounds__(256) void cvt_all(const float* __restrict__ x,
                                               const float* __restrict__ wq,
                                               const float* __restrict__ wk,
                                               const float* __restrict__ wv,
                                               const float* __restrict__ wo,
                                               u16* __restrict__ xb, u16* __restrict__ wqb,
                                               u16* __restrict__ wkb, u16* __restrict__ wvb,
                                               u16* __restrict__ wob) {
    size_t i = (size_t)blockIdx.x * 256 + threadIdx.x;
    const float* s; u16* d; size_t off;
    if      (i < 1048576) { s = x;  d = xb;  off = i; }
    else if (i < 1572864) { s = wq; d = wqb; off = i - 1048576; }
    else if (i < 1703936) { s = wk; d = wkb; off = i - 1572864; }
    else if (i < 1835008) { s = wv; d = wvb; off = i - 1703936; }
    else                  { s = wo; d = wob; off = i - 1835008; }
    const float* p = s + off * 8;
    float4 a = *(const float4*)p;
    float4 b = *(const float4*)(p + 4);
    union { unsigned u[4]; bf16x8 v; } r;
    r.u[0] = cvtpk(a.x, a.y);
    r.u[1] = cvtpk(a.z, a.w);
    r.u[2] = cvtpk(b.x, b.y);
    r.u[3] = cvtpk(b.z, b.w);
    *(bf16x8*)(d + off * 8) = r.v;
}

// ---------------- bf16 GEMM, 128M x 64N tiles (4 blocks/CU) ----------------
// Same inner pattern as the m97-style kernel; tile narrowed N 128->64 so the
// grid becomes (32,32)=1024 blocks = 4/CU (was 512 = 2/CU, grid-limited TLP —
// R6 data: identical inner loop ran 520 TF at 3 blocks/CU vs 344 TF at 2).
// Per XCD (x%8 mapping): 4 B-panels x 256KB = 1MB, L2-resident.
__global__ __launch_bounds__(256, 4) void gemm_bt64(const u16* __restrict__ A,
                                                    const u16* __restrict__ Bt,
                                                    float* __restrict__ C,
                                                    int M, int N, int K) {
    __shared__ u16 As[8192];    // 128 rows x 8 chunks
    __shared__ u16 Bs[4096];    // 64 rows x 8 chunks
    const int t = threadIdx.x;
    const int wave = t >> 6, lane = t & 63;
    const int wm = (wave >> 1) * 64, wn = (wave & 1) * 32;
    const int lhi = lane >> 4, llo = lane & 15;
    const int m0 = blockIdx.y * 128, n0 = blockIdx.x * 64;
    const int wbase = wave * 64;

    f32x4 acc[4][2] = {};
    for (int k0 = 0; k0 < K; k0 += 64) {
        const u16* Ab = A + (size_t)m0 * K + k0;
        const u16* Bb = Bt + (size_t)n0 * K + k0;
#pragma unroll
        for (int i = 0; i < 4; ++i) {
            int s = i * 256 + t;
            int row = s >> 3, gch = (s & 7) ^ (row & 7);
            dma16(Ab + (size_t)row * K + gch * 8, As + (i * 256 + wbase) * 8);
        }
#pragma unroll
        for (int i = 0; i < 2; ++i) {
            int s = i * 256 + t;
            int row = s >> 3, gch = (s & 7) ^ (row & 7);
            dma16(Bb + (size_t)row * K + gch * 8, Bs + (i * 256 + wbase) * 8);
        }
        __syncthreads();
#pragma unroll
        for (int ks = 0; ks < 2; ++ks) {
            const int kb = ks * 4 + lhi;
            bf16x8 af[4], bfg[2];
#pragma unroll
            for (int mi = 0; mi < 4; ++mi) af[mi] = sfrag(As, wm + mi * 16 + llo, kb);
#pragma unroll
            for (int ni = 0; ni < 2; ++ni) bfg[ni] = sfrag(Bs, wn + ni * 16 + llo, kb);
#pragma unroll
            for (int mi = 0; mi < 4; ++mi)
#pragma unroll
                for (int ni = 0; ni < 2; ++ni)
                    acc[mi][ni] = __builtin_amdgcn_mfma_f32_16x16x32_bf16(
                        af[mi], bfg[ni], acc[mi][ni], 0, 0, 0);
        }
        __syncthreads();
    }
#pragma unroll
    for (int mi = 0; mi < 4; ++mi)
#pragma unroll
        for (int ni = 0; ni < 2; ++ni)
#pragma unroll
            for (int r = 0; r < 4; ++r) {
                int row = m0 + wm + mi * 16 + lhi * 4 + r;
                int col = n0 + wn + ni * 16 + llo;
                C[(size_t)row * N + col] = acc[mi][ni][r];
            }
}

// ---------------- merged Q/K/V projection (verified R1/R6) ----------------
// bx 0..15: Q [4096][2048] bf16, PRE-SCALED by SCL | bx 16..19: K | bx 20..23: Vt
__global__ __launch_bounds__(256) void gemm_qkv(const u16* __restrict__ A,
                                                const u16* __restrict__ Wq,
                                                const u16* __restrict__ Wk,
                                                const u16* __restrict__ Wv,
                                                u16* __restrict__ Qout,
                                                u16* __restrict__ Kout,
                                                u16* __restrict__ Vtout) {
    const int K = 2048;
    __shared__ u16 As[8192];
    __shared__ u16 Bs[8192];
    const int t = threadIdx.x;
    const int wave = t >> 6, lane = t & 63;
    const int wm = (wave >> 1) * 64, wn = (wave & 1) * 64;
    const int lhi = lane >> 4, llo = lane & 15;
    const int m0 = blockIdx.y * 128;
    const int bx = blockIdx.x;
    const int kind = (bx < 16) ? 0 : (bx < 20 ? 1 : 2);
    const int n0 = (kind == 0) ? bx * 128 : (bx & 3) * 128;
    const u16* Bt = ((kind == 0) ? Wq : (kind == 1) ? Wk : Wv) + (size_t)n0 * K;
    const int wbase = wave * 64;

    f32x4 acc[4][4] = {};
    for (int k0 = 0; k0 < K; k0 += 64) {
        const u16* Ab = A + (size_t)m0 * K + k0;
        const u16* Bb = Bt + k0;
#pragma unroll
        for (int i = 0; i < 4; ++i) {
            int s = i * 256 + t;
            int row = s >> 3, gch = (s & 7) ^ (row & 7);
            dma16(Ab + (size_t)row * K + gch * 8, As + (i * 256 + wbase) * 8);
            dma16(Bb + (size_t)row * K + gch * 8, Bs + (i * 256 + wbase) * 8);
        }
        __syncthreads();
#pragma unroll
        for (int ks = 0; ks < 2; ++ks) {
            const int kb = ks * 4 + lhi;
            bf16x8 af[4], bfg[4];
#pragma unroll
            for (int mi = 0; mi < 4; ++mi) af[mi] = sfrag(As, wm + mi * 16 + llo, kb);
#pragma unroll
            for (int ni = 0; ni < 4; ++ni) bfg[ni] = sfrag(Bs, wn + ni * 16 + llo, kb);
#pragma unroll
            for (int mi = 0; mi < 4; ++mi)
#pragma unroll
                for (int ni = 0; ni < 4; ++ni)
                    acc[mi][ni] = __builtin_amdgcn_mfma_f32_16x16x32_bf16(
                        af[mi], bfg[ni], acc[mi][ni], 0, 0, 0);
        }
        __syncthreads();
    }

    if (kind == 0) {
#pragma unroll
        for (int mi = 0; mi < 4; ++mi)
#pragma unroll
            for (int ni = 0; ni < 4; ++ni)
#pragma unroll
                for (int r = 0; r < 4; ++r) {
                    int row = m0 + wm + mi * 16 + lhi * 4 + r;
                    int col = n0 + wn + ni * 16 + llo;
                    Qout[(size_t)row * 2048 + col] = f2bf(acc[mi][ni][r] * SCL);
                }
    } else if (kind == 1) {
#pragma unroll
        for (int mi = 0; mi < 4; ++mi)
#pragma unroll
            for (int ni = 0; ni < 4; ++ni)
#pragma unroll
                for (int r = 0; r < 4; ++r) {
                    int row = m0 + wm + mi * 16 + lhi * 4 + r;
                    int col = n0 + wn + ni * 16 + llo;
                    Kout[(size_t)row * 512 + col] = f2bf(acc[mi][ni][r]);
                }
    } else {
        // Vt[b][g][hd][s]: off = (col + (row>>11)*512)*2048 + (row&2047)
#pragma unroll
        for (int mi = 0; mi < 4; ++mi)
#pragma unroll
            for (int ni = 0; ni < 4; ++ni) {
                int row = m0 + wm + mi * 16 + lhi * 4;
                int col = n0 + wn + ni * 16 + llo;
                size_t off = ((size_t)col + (size_t)(row >> 11) * 512) * 2048 + (row & 2047);
                union { unsigned u[2]; short4 s; } v;
                v.u[0] = cvtpk(acc[mi][ni][0], acc[mi][ni][1]);
                v.u[1] = cvtpk(acc[mi][ni][2], acc[mi][ni][3]);
                *(short4*)(Vtout + off) = v.s;
            }
    }
}

// ---------------- flash GQA attention v6 (verified R1/R6, ~89us) ----------------
__global__ __launch_bounds__(256, 4) void attn6(const u16* __restrict__ Q,
                                                const u16* __restrict__ Kbuf,
                                                const u16* __restrict__ Vtb,
                                                u16* __restrict__ Ctx) {
    __shared__ u16 Ks[2][4096];
    __shared__ u16 Vs[2][4096];
    const int bg = blockIdx.y;
    const int b = bg >> 3, g = bg & 7;
    const int t = threadIdx.x, w = t >> 6, lane = t & 63;
    const int lhi = lane >> 4, llo = lane & 15;
    const int h = g * 4 + w;
    const int wbase = w * 64;

    const u16* Kp = Kbuf + (size_t)(b * 2048) * 512 + g * 64;
    const u16* Vp = Vtb + (size_t)bg * 64 * 2048;

    const int r0 = t >> 3,          g0 = (t & 7) ^ (r0 & 7);
    const int r1 = (256 + t) >> 3,  g1 = ((256 + t) & 7) ^ (r1 & 7);

    bf16x4 ones;
    ones[0] = ones[1] = ones[2] = ones[3] = (short)0x3F80;

    auto STAGE = [&](int kt, int bufi) {
        const u16* Kt = Kp + (size_t)kt * 64 * 512;
        const u16* Vt2 = Vp + kt * 64;
        u16* Kd = Ks[bufi]; u16* Vd = Vs[bufi];
        dma16(Kt + (size_t)r0 * 512 + g0 * 8, Kd + wbase * 8);
        dma16(Vt2 + (size_t)r0 * 2048 + g0 * 8, Vd + wbase * 8);
        dma16(Kt + (size_t)r1 * 512 + g1 * 8, Kd + (256 + wbase) * 8);
        dma16(Vt2 + (size_t)r1 * 2048 + g1 * 8, Vd + (256 + wbase) * 8);
    };

#pragma unroll
    for (int ph = 0; ph < 2; ++ph) {
        const int qt = ph ? (int)blockIdx.x : 127 - (int)blockIdx.x;

        const u16* Qp = Q + ((size_t)(b * 2048 + qt * 16)) * 2048 + h * 64;
        bf16x8 aq[2];
#pragma unroll
        for (int ks = 0; ks < 2; ++ks)
            aq[ks] = *(const bf16x8*)(Qp + (size_t)llo * 2048 + ks * 32 + lhi * 8);

        f32x4 o[4] = {};
        f32x4 lac = {};
        float m_ = NEG_BIG;

        const int ktmax = (qt * 16 + 15) >> 6;

        STAGE(0, 0);
        asm volatile("s_waitcnt vmcnt(0)" ::: "memory");
        __builtin_amdgcn_s_barrier();

        for (int kt = 0; kt <= ktmax; ++kt) {
            const int cur = kt & 1;
            if (kt < ktmax) STAGE(kt + 1, cur ^ 1);
            const u16* Ksb = Ks[cur];
            const u16* Vsb = Vs[cur];

            f32x4 st[4] = {};
            __builtin_amdgcn_s_setprio(1);
#pragma unroll
            for (int ks = 0; ks < 2; ++ks) {
                const int kb8 = ks * 4 + lhi;
                bf16x8 kf[4];
#pragma unroll
                for (int kb = 0; kb < 4; ++kb) kf[kb] = sfrag(Ksb, kb * 16 + llo, kb8);
#pragma unroll
                for (int kb = 0; kb < 4; ++kb)
                    st[kb] = __builtin_amdgcn_mfma_f32_16x16x32_bf16(
                        kf[kb], aq[ks], st[kb], 0, 0, 0);
            }
            __builtin_amdgcn_s_setprio(0);

            if (kt * 64 + 63 > qt * 16) {
                int qg = qt * 16 + llo;
#pragma unroll
                for (int kb = 0; kb < 4; ++kb)
#pragma unroll
                    for (int r = 0; r < 4; ++r) {
                        int kg = kt * 64 + kb * 16 + lhi * 4 + r;
                        if (kg > qg) st[kb][r] = NEG_BIG;
                    }
            }

            float t0 = fmaxf(fmaxf(st[0][0], st[0][1]), st[0][2]);
            float t1 = fmaxf(fmaxf(st[0][3], st[1][0]), st[1][1]);
            float t2 = fmaxf(fmaxf(st[1][2], st[1][3]), st[2][0]);
            float t3 = fmaxf(fmaxf(st[2][1], st[2][2]), st[2][3]);
            float t4 = fmaxf(fmaxf(st[3][0], st[3][1]), st[3][2]);
            float mx = fmaxf(fmaxf(fmaxf(t0, t1), t2),
                             fmaxf(fmaxf(t3, t4), st[3][3]));
            mx = fmaxf(mx, __shfl_xor(mx, 16, 64));
            mx = fmaxf(mx, __shfl_xor(mx, 32, 64));

            if (__any(mx > m_ + 8.0f)) {
                float mn = fmaxf(m_, mx);
                float alpha = exp2f(m_ - mn);
                m_ = mn;
#pragma unroll
                for (int hb = 0; hb < 4; ++hb) o[hb] *= alpha;
                lac *= alpha;
            }

            bf16x4 pf[4];
#pragma unroll
            for (int kb = 0; kb < 4; ++kb) {
                float p0 = exp2f(st[kb][0] - m_);
                float p1 = exp2f(st[kb][1] - m_);
                float p2 = exp2f(st[kb][2] - m_);
                float p3 = exp2f(st[kb][3] - m_);
                union { unsigned u[2]; bf16x4 v; } pu;
                pu.u[0] = cvtpk(p0, p1);
                pu.u[1] = cvtpk(p2, p3);
                pf[kb] = pu.v;
            }

            __builtin_amdgcn_s_setprio(1);
#pragma unroll
            for (int kb = 0; kb < 4; ++kb) lac = mfma16(ones, pf[kb], lac);
#pragma unroll
            for (int kb = 0; kb < 4; ++kb)
#pragma unroll
                for (int hb = 0; hb < 4; ++hb)
                    o[hb] = mfma16(vfrag(Vsb, hb * 16 + llo, kb, lhi), pf[kb], o[hb]);
            __builtin_amdgcn_s_setprio(0);

            asm volatile("s_waitcnt vmcnt(0)" ::: "memory");
            __builtin_amdgcn_s_barrier();
        }

        float inv = 1.0f / lac[0];
        u16* Cp = Ctx + (size_t)(b * 2048 + qt * 16) * 2048 + h * 64;
#pragma unroll
        for (int hb = 0; hb < 4; ++hb) {
            union { unsigned u[2]; short4 s; } cu;
            cu.u[0] = cvtpk(o[hb][0] * inv, o[hb][1] * inv);
            cu.u[1] = cvtpk(o[hb][2] * inv, o[hb][3] * inv);
            *(short4*)(Cp + (size_t)llo * 2048 + hb * 16 + lhi * 4) = cu.s;
        }
    }
}

extern "C" void kernel_launch(void* const* d_in, const int* in_sizes, int n_in,
                              void* d_out, int out_size, void* d_ws, size_t ws_size,
                              hipStream_t stream) {
    const float* x  = (const float*)d_in[0];
    const float* Wq = (const float*)d_in[1];
    const float* Wk = (const float*)d_in[2];
    const float* Wv = (const float*)d_in[3];
    const float* Wo = (const float*)d_in[4];

    u16* xb  = (u16*)d_ws;
    u16* wqb = xb + 8388608;
    u16* wkb = wqb + 4194304;
    u16* wvb = wkb + 1048576;
    u16* wob = wvb + 1048576;
    u16* Kb  = wob + 4194304;
    u16* Vtb = Kb + 2097152;
    u16* Ctx = xb;               // overlay (xb dead after projections)
    u16* Qb  = (u16*)d_out;      // bf16 Q staged in fp32 out buffer
    float* out = (float*)d_out;

    cvt_all<<<dim3(9216), 256, 0, stream>>>(x, Wq, Wk, Wv, Wo, xb, wqb, wkb, wvb, wob);
    gemm_qkv<<<dim3(24, 32), 256, 0, stream>>>(xb, wqb, wkb, wvb, Qb, Kb, Vtb);
    attn6<<<dim3(64, 16), 256, 0, stream>>>(Qb, Kb, Vtb, Ctx);
    gemm_bt64<<<dim3(32, 32), 256, 0, stream>>>(Ctx, wob, out, 4096, 2048, 2048);
}

// Round 10
// 306.483 us; speedup vs baseline: 1.1891x; 1.0460x over previous
//
#include <hip/hip_runtime.h>
#include <hip/hip_bf16.h>

typedef unsigned short u16;
typedef short bf16x4 __attribute__((ext_vector_type(4)));
typedef short bf16x8 __attribute__((ext_vector_type(8)));
typedef float f32x4 __attribute__((ext_vector_type(4)));

#define NEG_BIG (-1e30f)
#define SCL 0.18033688f   // 0.125 * log2(e): Q pre-scaled so scores are in log2 units

__device__ __forceinline__ u16 f2bf(float f) {
    union { float f; unsigned int u; } x; x.f = f;
    unsigned int r = x.u + 0x7fffu + ((x.u >> 16) & 1u);
    return (u16)(r >> 16);
}

// hardware RNE pack of two f32 -> 2x bf16 in one u32 (T12 primitive)
__device__ __forceinline__ unsigned cvtpk(float lo, float hi) {
    unsigned r;
    asm("v_cvt_pk_bf16_f32 %0, %1, %2" : "=v"(r) : "v"(lo), "v"(hi));
    return r;
}

__device__ __forceinline__ f32x4 mfma16(bf16x4 a, bf16x4 b, f32x4 c) {
#if __has_builtin(__builtin_amdgcn_mfma_f32_16x16x16bf16_1k)
    return __builtin_amdgcn_mfma_f32_16x16x16bf16_1k(a, b, c, 0, 0, 0);
#else
    asm("v_mfma_f32_16x16x16_bf16 %0, %1, %2, %0" : "+v"(c) : "v"(a), "v"(b));
    return c;
#endif
}

__device__ __forceinline__ void dma16(const u16* g, const u16* lds) {
    __builtin_amdgcn_global_load_lds(
        (const __attribute__((address_space(1))) unsigned int*)g,
        (__attribute__((address_space(3))) unsigned int*)lds, 16, 0, 0);
}

__device__ __forceinline__ bf16x8 sfrag(const u16* lds, int row, int kb8) {
    int slot = row * 8 + (kb8 ^ (row & 7));
    return *(const bf16x8*)(lds + slot * 8);
}

// b64 V^T fragment for 16x16x16 PV
__device__ __forceinline__ bf16x4 vfrag(const u16* lds, int row, int kb, int lhi) {
    int c = kb * 2 + (lhi >> 1);
    int slot = row * 8 + (c ^ (row & 7));
    return *(const bf16x4*)(lds + slot * 8 + (lhi & 1) * 4);
}

// ---------------- fused fp32 -> bf16 convert ----------------
__global__ __launch_bounds__(256) void cvt_all(const float* __restrict__ x,
                                               const float* __restrict__ wq,
                                               const float* __restrict__ wk,
                                               const float* __restrict__ wv,
                                               const float* __restrict__ wo,
                                               u16* __restrict__ xb, u16* __restrict__ wqb,
                                               u16* __restrict__ wkb, u16* __restrict__ wvb,
                                               u16* __restrict__ wob) {
    size_t i = (size_t)blockIdx.x * 256 + threadIdx.x;
    const float* s; u16* d; size_t off;
    if      (i < 1048576) { s = x;  d = xb;  off = i; }
    else if (i < 1572864) { s = wq; d = wqb; off = i - 1048576; }
    else if (i < 1703936) { s = wk; d = wkb; off = i - 1572864; }
    else if (i < 1835008) { s = wv; d = wvb; off = i - 1703936; }
    else                  { s = wo; d = wob; off = i - 1835008; }
    const float* p = s + off * 8;
    float4 a = *(const float4*)p;
    float4 b = *(const float4*)(p + 4);
    bf16x8 r;
    r[0] = (short)f2bf(a.x); r[1] = (short)f2bf(a.y);
    r[2] = (short)f2bf(a.z); r[3] = (short)f2bf(a.w);
    r[4] = (short)f2bf(b.x); r[5] = (short)f2bf(b.y);
    r[6] = (short)f2bf(b.z); r[7] = (short)f2bf(b.w);
    *(bf16x8*)(d + off * 8) = r;
}

// ---------------- bf16 GEMM (m97-style), fp32 output ----------------
__global__ __launch_bounds__(256) void gemm_bt(const u16* __restrict__ A,
                                               const u16* __restrict__ Bt,
                                               float* __restrict__ C,
                                               int M, int N, int K) {
    __shared__ u16 As[8192];
    __shared__ u16 Bs[8192];
    const int t = threadIdx.x;
    const int wave = t >> 6, lane = t & 63;
    const int wm = (wave >> 1) * 64, wn = (wave & 1) * 64;
    const int lhi = lane >> 4, llo = lane & 15;
    const int m0 = blockIdx.y * 128, n0 = blockIdx.x * 128;
    const int wbase = wave * 64;

    f32x4 acc[4][4] = {};
    for (int k0 = 0; k0 < K; k0 += 64) {
        const u16* Ab = A + (size_t)m0 * K + k0;
        const u16* Bb = Bt + (size_t)n0 * K + k0;
#pragma unroll
        for (int i = 0; i < 4; ++i) {
            int s = i * 256 + t;
            int row = s >> 3, gch = (s & 7) ^ (row & 7);
            dma16(Ab + (size_t)row * K + gch * 8, As + (i * 256 + wbase) * 8);
            dma16(Bb + (size_t)row * K + gch * 8, Bs + (i * 256 + wbase) * 8);
        }
        __syncthreads();
#pragma unroll
        for (int ks = 0; ks < 2; ++ks) {
            const int kb = ks * 4 + lhi;
            bf16x8 af[4], bfg[4];
#pragma unroll
            for (int mi = 0; mi < 4; ++mi) af[mi] = sfrag(As, wm + mi * 16 + llo, kb);
#pragma unroll
            for (int ni = 0; ni < 4; ++ni) bfg[ni] = sfrag(Bs, wn + ni * 16 + llo, kb);
#pragma unroll
            for (int mi = 0; mi < 4; ++mi)
#pragma unroll
                for (int ni = 0; ni < 4; ++ni)
                    acc[mi][ni] = __builtin_amdgcn_mfma_f32_16x16x32_bf16(
                        af[mi], bfg[ni], acc[mi][ni], 0, 0, 0);
        }
        __syncthreads();
    }
#pragma unroll
    for (int mi = 0; mi < 4; ++mi)
#pragma unroll
        for (int ni = 0; ni < 4; ++ni)
#pragma unroll
            for (int r = 0; r < 4; ++r) {
                int row = m0 + wm + mi * 16 + lhi * 4 + r;
                int col = n0 + wn + ni * 16 + llo;
                C[(size_t)row * N + col] = acc[mi][ni][r];
            }
}

// ---------------- merged Q/K/V projection ----------------
// bx 0..15: Q [4096][2048] bf16, PRE-SCALED by SCL | bx 16..19: K | bx 20..23: Vt
__global__ __launch_bounds__(256) void gemm_qkv(const u16* __restrict__ A,
                                                const u16* __restrict__ Wq,
                                                const u16* __restrict__ Wk,
                                                const u16* __restrict__ Wv,
                                                u16* __restrict__ Qout,
                                                u16* __restrict__ Kout,
                                                u16* __restrict__ Vtout) {
    const int K = 2048;
    __shared__ u16 As[8192];
    __shared__ u16 Bs[8192];
    const int t = threadIdx.x;
    const int wave = t >> 6, lane = t & 63;
    const int wm = (wave >> 1) * 64, wn = (wave & 1) * 64;
    const int lhi = lane >> 4, llo = lane & 15;
    const int m0 = blockIdx.y * 128;
    const int bx = blockIdx.x;
    const int kind = (bx < 16) ? 0 : (bx < 20 ? 1 : 2);
    const int n0 = (kind == 0) ? bx * 128 : (bx & 3) * 128;
    const u16* Bt = ((kind == 0) ? Wq : (kind == 1) ? Wk : Wv) + (size_t)n0 * K;
    const int wbase = wave * 64;

    f32x4 acc[4][4] = {};
    for (int k0 = 0; k0 < K; k0 += 64) {
        const u16* Ab = A + (size_t)m0 * K + k0;
        const u16* Bb = Bt + k0;
#pragma unroll
        for (int i = 0; i < 4; ++i) {
            int s = i * 256 + t;
            int row = s >> 3, gch = (s & 7) ^ (row & 7);
            dma16(Ab + (size_t)row * K + gch * 8, As + (i * 256 + wbase) * 8);
            dma16(Bb + (size_t)row * K + gch * 8, Bs + (i * 256 + wbase) * 8);
        }
        __syncthreads();
#pragma unroll
        for (int ks = 0; ks < 2; ++ks) {
            const int kb = ks * 4 + lhi;
            bf16x8 af[4], bfg[4];
#pragma unroll
            for (int mi = 0; mi < 4; ++mi) af[mi] = sfrag(As, wm + mi * 16 + llo, kb);
#pragma unroll
            for (int ni = 0; ni < 4; ++ni) bfg[ni] = sfrag(Bs, wn + ni * 16 + llo, kb);
#pragma unroll
            for (int mi = 0; mi < 4; ++mi)
#pragma unroll
                for (int ni = 0; ni < 4; ++ni)
                    acc[mi][ni] = __builtin_amdgcn_mfma_f32_16x16x32_bf16(
                        af[mi], bfg[ni], acc[mi][ni], 0, 0, 0);
        }
        __syncthreads();
    }

    if (kind == 0) {
#pragma unroll
        for (int mi = 0; mi < 4; ++mi)
#pragma unroll
            for (int ni = 0; ni < 4; ++ni)
#pragma unroll
                for (int r = 0; r < 4; ++r) {
                    int row = m0 + wm + mi * 16 + lhi * 4 + r;
                    int col = n0 + wn + ni * 16 + llo;
                    Qout[(size_t)row * 2048 + col] = f2bf(acc[mi][ni][r] * SCL);
                }
    } else if (kind == 1) {
#pragma unroll
        for (int mi = 0; mi < 4; ++mi)
#pragma unroll
            for (int ni = 0; ni < 4; ++ni)
#pragma unroll
                for (int r = 0; r < 4; ++r) {
                    int row = m0 + wm + mi * 16 + lhi * 4 + r;
                    int col = n0 + wn + ni * 16 + llo;
                    Kout[(size_t)row * 512 + col] = f2bf(acc[mi][ni][r]);
                }
    } else {
        // Vt[b][g][hd][s]: off = (col + (row>>11)*512)*2048 + (row&2047)
#pragma unroll
        for (int mi = 0; mi < 4; ++mi)
#pragma unroll
            for (int ni = 0; ni < 4; ++ni) {
                int row = m0 + wm + mi * 16 + lhi * 4;
                int col = n0 + wn + ni * 16 + llo;
                size_t off = ((size_t)col + (size_t)(row >> 11) * 512) * 2048 + (row & 2047);
                short4 v;
                v.x = (short)f2bf(acc[mi][ni][0]);
                v.y = (short)f2bf(acc[mi][ni][1]);
                v.z = (short)f2bf(acc[mi][ni][2]);
                v.w = (short)f2bf(acc[mi][ni][3]);
                *(short4*)(Vtout + off) = v;
            }
    }
}

// ---------------- flash GQA attention v6 ----------------
//  - P stays IN REGISTERS: 16x16x32 QK^T D-layout (row=(lane>>4)*4+r) == 16x16x16
//    B-operand k-layout, so cvt_pk(st) feeds PV directly. No P LDS round-trip.
//  - row-sum l via ones-A 16x16x16 MFMA.
//  - defer-max THR=8 (log2 units): O/l rescale only when the running max grows.
//  - double-buffered K/V staging: STAGE(next); compute(cur); vmcnt(0); barrier.
__global__ __launch_bounds__(256, 4) void attn6(const u16* __restrict__ Q,
                                                const u16* __restrict__ Kbuf,
                                                const u16* __restrict__ Vtb,
                                                u16* __restrict__ Ctx) {
    __shared__ u16 Ks[2][4096];
    __shared__ u16 Vs[2][4096];
    const int bg = blockIdx.y;
    const int b = bg >> 3, g = bg & 7;
    const int t = threadIdx.x, w = t >> 6, lane = t & 63;
    const int lhi = lane >> 4, llo = lane & 15;
    const int h = g * 4 + w;
    const int wbase = w * 64;

    const u16* Kp = Kbuf + (size_t)(b * 2048) * 512 + g * 64;
    const u16* Vp = Vtb + (size_t)bg * 64 * 2048;

    const int r0 = t >> 3,          g0 = (t & 7) ^ (r0 & 7);
    const int r1 = (256 + t) >> 3,  g1 = ((256 + t) & 7) ^ (r1 & 7);

    bf16x4 ones;
    ones[0] = ones[1] = ones[2] = ones[3] = (short)0x3F80;   // bf16 1.0

    auto STAGE = [&](int kt, int bufi) {
        const u16* Kt = Kp + (size_t)kt * 64 * 512;
        const u16* Vt2 = Vp + kt * 64;
        u16* Kd = Ks[bufi]; u16* Vd = Vs[bufi];
        dma16(Kt + (size_t)r0 * 512 + g0 * 8, Kd + wbase * 8);
        dma16(Vt2 + (size_t)r0 * 2048 + g0 * 8, Vd + wbase * 8);
        dma16(Kt + (size_t)r1 * 512 + g1 * 8, Kd + (256 + wbase) * 8);
        dma16(Vt2 + (size_t)r1 * 2048 + g1 * 8, Vd + (256 + wbase) * 8);
    };

#pragma unroll
    for (int ph = 0; ph < 2; ++ph) {
        const int qt = ph ? (int)blockIdx.x : 127 - (int)blockIdx.x;

        const u16* Qp = Q + ((size_t)(b * 2048 + qt * 16)) * 2048 + h * 64;
        bf16x8 aq[2];
#pragma unroll
        for (int ks = 0; ks < 2; ++ks)
            aq[ks] = *(const bf16x8*)(Qp + (size_t)llo * 2048 + ks * 32 + lhi * 8);

        f32x4 o[4] = {};          // O^T: lane q=llo, hd=hb*16+lhi*4+r
        f32x4 lac = {};           // l (row-sum), replicated over r
        float m_ = NEG_BIG;

        const int ktmax = (qt * 16 + 15) >> 6;

        STAGE(0, 0);
        asm volatile("s_waitcnt vmcnt(0)" ::: "memory");
        __builtin_amdgcn_s_barrier();

        for (int kt = 0; kt <= ktmax; ++kt) {
            const int cur = kt & 1;
            if (kt < ktmax) STAGE(kt + 1, cur ^ 1);     // prefetch next tile
            const u16* Ksb = Ks[cur];
            const u16* Vsb = Vs[cur];

            // S^T = K Q^T : st[kb], D[m=k][n=q] (log2 units)
            f32x4 st[4] = {};
            __builtin_amdgcn_s_setprio(1);
#pragma unroll
            for (int ks = 0; ks < 2; ++ks) {
                const int kb8 = ks * 4 + lhi;
                bf16x8 kf[4];
#pragma unroll
                for (int kb = 0; kb < 4; ++kb) kf[kb] = sfrag(Ksb, kb * 16 + llo, kb8);
#pragma unroll
                for (int kb = 0; kb < 4; ++kb)
                    st[kb] = __builtin_amdgcn_mfma_f32_16x16x32_bf16(
                        kf[kb], aq[ks], st[kb], 0, 0, 0);
            }
            __builtin_amdgcn_s_setprio(0);

            // causal mask (only diagonal tiles pay)
            if (kt * 64 + 63 > qt * 16) {
                int qg = qt * 16 + llo;
#pragma unroll
                for (int kb = 0; kb < 4; ++kb)
#pragma unroll
                    for (int r = 0; r < 4; ++r) {
                        int kg = kt * 64 + kb * 16 + lhi * 4 + r;
                        if (kg > qg) st[kb][r] = NEG_BIG;
                    }
            }

            // per-q max: max3 tree + 2 shfl
            float t0 = fmaxf(fmaxf(st[0][0], st[0][1]), st[0][2]);
            float t1 = fmaxf(fmaxf(st[0][3], st[1][0]), st[1][1]);
            float t2 = fmaxf(fmaxf(st[1][2], st[1][3]), st[2][0]);
            float t3 = fmaxf(fmaxf(st[2][1], st[2][2]), st[2][3]);
            float t4 = fmaxf(fmaxf(st[3][0], st[3][1]), st[3][2]);
            float mx = fmaxf(fmaxf(fmaxf(t0, t1), t2),
                             fmaxf(fmaxf(t3, t4), st[3][3]));
            mx = fmaxf(mx, __shfl_xor(mx, 16, 64));
            mx = fmaxf(mx, __shfl_xor(mx, 32, 64));

            // defer-max: rescale only when max grew by >8 (log2) for any q-row
            if (__any(mx > m_ + 8.0f)) {
                float mn = fmaxf(m_, mx);
                float alpha = exp2f(m_ - mn);
                m_ = mn;
#pragma unroll
                for (int hb = 0; hb < 4; ++hb) o[hb] *= alpha;
                lac *= alpha;
            }

            // P = exp2(S - m) in registers -> PV B-fragments (no LDS, no shuffle)
            bf16x4 pf[4];
#pragma unroll
            for (int kb = 0; kb < 4; ++kb) {
                float p0 = exp2f(st[kb][0] - m_);
                float p1 = exp2f(st[kb][1] - m_);
                float p2 = exp2f(st[kb][2] - m_);
                float p3 = exp2f(st[kb][3] - m_);
                union { unsigned u[2]; bf16x4 v; } pu;
                pu.u[0] = cvtpk(p0, p1);
                pu.u[1] = cvtpk(p2, p3);
                pf[kb] = pu.v;
            }

            __builtin_amdgcn_s_setprio(1);
#pragma unroll
            for (int kb = 0; kb < 4; ++kb) lac = mfma16(ones, pf[kb], lac);
#pragma unroll
            for (int kb = 0; kb < 4; ++kb)
#pragma unroll
                for (int hb = 0; hb < 4; ++hb)
                    o[hb] = mfma16(vfrag(Vsb, hb * 16 + llo, kb, lhi), pf[kb], o[hb]);
            __builtin_amdgcn_s_setprio(0);

            asm volatile("s_waitcnt vmcnt(0)" ::: "memory");  // next tile landed
            __builtin_amdgcn_s_barrier();
        }

        // epilogue: lane q = qt*16+llo, hd = hb*16+lhi*4+r
        float inv = 1.0f / lac[0];
        u16* Cp = Ctx + (size_t)(b * 2048 + qt * 16) * 2048 + h * 64;
#pragma unroll
        for (int hb = 0; hb < 4; ++hb) {
            union { unsigned u[2]; short4 s; } cu;
            cu.u[0] = cvtpk(o[hb][0] * inv, o[hb][1] * inv);
            cu.u[1] = cvtpk(o[hb][2] * inv, o[hb][3] * inv);
            *(short4*)(Cp + (size_t)llo * 2048 + hb * 16 + lhi * 4) = cu.s;
        }
    }
}

extern "C" void kernel_launch(void* const* d_in, const int* in_sizes, int n_in,
                              void* d_out, int out_size, void* d_ws, size_t ws_size,
                              hipStream_t stream) {
    const float* x  = (const float*)d_in[0];
    const float* Wq = (const float*)d_in[1];
    const float* Wk = (const float*)d_in[2];
    const float* Wv = (const float*)d_in[3];
    const float* Wo = (const float*)d_in[4];

    u16* xb  = (u16*)d_ws;
    u16* wqb = xb + 8388608;
    u16* wkb = wqb + 4194304;
    u16* wvb = wkb + 1048576;
    u16* wob = wvb + 1048576;
    u16* Kb  = wob + 4194304;
    u16* Vtb = Kb + 2097152;
    u16* Ctx = xb;               // overlay (xb dead after projections)
    u16* Qb  = (u16*)d_out;      // bf16 Q staged in fp32 out buffer
    float* out = (float*)d_out;

    cvt_all<<<dim3(9216), 256, 0, stream>>>(x, Wq, Wk, Wv, Wo, xb, wqb, wkb, wvb, wob);
    gemm_qkv<<<dim3(24, 32), 256, 0, stream>>>(xb, wqb, wkb, wvb, Qb, Kb, Vtb);
    attn6<<<dim3(64, 16), 256, 0, stream>>>(Qb, Kb, Vtb, Ctx);
    gemm_bt<<<dim3(16, 32), 256, 0, stream>>>(Ctx, wob, out, 4096, 2048, 2048);
}